// Round 12
// baseline (107.275 us; speedup 1.0000x reference)
//
#include <hip/hip_runtime.h>
#include <hip/hip_bf16.h>

#define HH 256
#define WW 256
#define CC 128
#define NN 4
#define NSS 5
#define LN2F 0.6931471805599453f
#define FSCALE 3.79828245f      // sqrt(10*log2(e)); dot scales by 14.4269504089
#define EPSI 1e-6f
#define ROWB (WW * CC * 2)      // 65536 B per image row (256 px * 256 B)
#define WBYTES 8192             // 32 cols * 256 B private window per row

typedef __attribute__((ext_vector_type(4))) float f32x4;
typedef __attribute__((ext_vector_type(8))) short short8v;

__device__ __forceinline__ void gload_lds16(const void* g, void* l) {
    __builtin_amdgcn_global_load_lds(
        (const __attribute__((address_space(1))) unsigned int*)g,
        (__attribute__((address_space(3))) unsigned int*)l, 16, 0, 0);
}

__device__ __forceinline__ float fast_exp2(float x) {
    float r;
    asm("v_exp_f32 %0, %1" : "=v"(r) : "v"(x));
    return r;
}
__device__ __forceinline__ float fast_log2(float x) {
    float r;
    asm("v_log_f32 %0, %1" : "=v"(r) : "v"(x));
    return r;
}

// ---------------- Kernel A: L2-normalize over C (x FSCALE), NCHW(f32) -> NHWC(bf16) -------
// granule-swizzled: 16B granule g of pixel w stored at slot g^(w&7)
__global__ __launch_bounds__(256) void norm_pack(const float* __restrict__ feat,
                                                 __hip_bfloat16* __restrict__ out) {
    __shared__ float lds[64][CC + 2];
    __shared__ float psum[4][64];
    __shared__ float inv[64];
    int bid = blockIdx.x;            // n*1024 + h*4 + wq
    int wq = bid & 3;
    int h = (bid >> 2) & 255;
    int n = bid >> 10;
    int tid = threadIdx.x;
    int p = tid & 63;
    int cg = tid >> 6;
    size_t base = ((size_t)(n * CC) * HH + h) * WW + wq * 64 + p;
    float ss = 0.f;
    #pragma unroll
    for (int i = 0; i < 32; ++i) {
        int c = cg * 32 + i;
        float v = feat[base + (size_t)c * (HH * WW)];
        lds[p][c] = v;
        ss += v * v;
    }
    psum[cg][p] = ss;
    __syncthreads();
    if (tid < 64) {
        float s = psum[0][tid] + psum[1][tid] + psum[2][tid] + psum[3][tid];
        inv[tid] = FSCALE / fmaxf(sqrtf(s), 1e-12f);
    }
    __syncthreads();
    __hip_bfloat16* dst = out + (((size_t)n * HH + h) * WW + wq * 64) * CC;
    #pragma unroll
    for (int k = 0; k < 4; ++k) {
        int j = (k * 256 + tid) * 8;
        int pp = j >> 7;
        int c0 = j & 127;
        int g = c0 >> 3;
        int gs = g ^ (pp & 7);           // (wq*64+pp)&7 == pp&7
        float iv = inv[pp];
        __hip_bfloat16 tmp[8];
        #pragma unroll
        for (int i = 0; i < 8; ++i)
            tmp[i] = __float2bfloat16(lds[pp][c0 + i] * iv);
        *(uint4*)(dst + pp * 128 + gs * 8) = *(uint4*)tmp;
    }
}

// ---------------- Kernel B: BARRIER-FREE wave-private banded-Gram MFMA loss ----------------
// Block = ONE wave (64 thr) = 4 own rows x 16 cols. The wave stages its private
// 32-col window (8KB/row: exactly its two B-tiles at wbase-8 / wbase+8) into its
// own 2x8KB LDS double-buffer via global_load_lds, paced ONLY by per-wave
// s_waitcnt vmcnt(8): zero s_barrier / __syncthreads in the whole kernel.
// 4096 blocks, 16KB LDS each -> 10 waves/CU resident, all self-paced.
// Select-before-exp (msel); masks/weights deferred to epilogue; features
// pre-scaled so exp(logit)=2^d; granule-XOR global layout (g^(w&7)).
// C layout (m89): col=lane&15 (neighbor), row=(lane>>4)*4+reg (own).
__global__ __launch_bounds__(64) void loss_mfma(const char* __restrict__ fn,
                                                float* __restrict__ out) {
    extern __shared__ char smem[];
    int bid = blockIdx.x;
    int swz = (bid & 7) * 512 + (bid >> 3);   // 4096 blocks, bijective XCD swizzle
    int n  = swz >> 10;
    int rg = (swz >> 4) & 63;
    int cg = swz & 15;
    int row0 = rg * 4;
    int wbase = cg * 16;
    int sc0 = wbase - 8;
    int lane = threadIdx.x;
    int nloc = lane & 15, kq = lane >> 4;

    const char* img = fn + (size_t)n * ((size_t)HH * ROWB);

    // A fragments: own rows row0..row0+3 at col wbase+nloc (swizzled layout)
    short8v a0[4], a1[4], a2[4], a3[4];
    {
        int px = wbase + nloc;
        const char* pb = img + (size_t)row0 * ROWB + px * 256;
        #pragma unroll
        for (int kb = 0; kb < 4; ++kb) a0[kb] = *(const short8v*)(pb + (((kb * 4 + kq) ^ (px & 7)) << 4));
        pb += ROWB;
        #pragma unroll
        for (int kb = 0; kb < 4; ++kb) a1[kb] = *(const short8v*)(pb + (((kb * 4 + kq) ^ (px & 7)) << 4));
        pb += ROWB;
        #pragma unroll
        for (int kb = 0; kb < 4; ++kb) a2[kb] = *(const short8v*)(pb + (((kb * 4 + kq) ^ (px & 7)) << 4));
        pb += ROWB;
        #pragma unroll
        for (int kb = 0; kb < 4; ++kb) a3[kb] = *(const short8v*)(pb + (((kb * 4 + kq) ^ (px & 7)) << 4));
    }

    // B-fragment LDS offsets within the 32-col window (tile0 = cols 0-15, tile1 = 16-31)
    int boff[2][4];
    #pragma unroll
    for (int j = 0; j < 2; ++j) {
        int lcol = j * 16 + nloc;                 // window-local col 0..31
        int cc = min(max(sc0 + lcol, 0), WW - 1); // pixel actually stored there
        #pragma unroll
        for (int kb = 0; kb < 4; ++kb)
            boff[j][kb] = lcol * 256 + (((kb * 4 + kq) ^ (cc & 7)) << 4);
    }

    // selection (tile1 valid?) + any-valid bits per rr; dy/row-invariant
    unsigned msel = 0, mb = 0;
    #pragma unroll
    for (int rr = 0; rr < 4; ++rr) {
        int rm = kq * 4 + rr;
        int dx0 = -8 + nloc - rm, dx1 = 8 + nloc - rm;
        int nc0 = wbase - 8 + nloc, nc1 = wbase + 8 + nloc;
        bool v0 = dx0 >= -NSS && dx0 <= NSS && nc0 >= 0 && nc0 < WW;
        bool v1 = dx1 >= -NSS && dx1 <= NSS && nc1 >= 0 && nc1 < WW;
        if (v1) msel |= 1u << rr;
        if (v0 || v1) mb |= 1u << rr;
    }

    // staging source offsets: 512 16B units, 8 per lane (unit = i*64+lane)
    int ssrc[8];
    #pragma unroll
    for (int i = 0; i < 8; ++i) {
        int u = i * 64 + lane;
        int lc = u >> 4;                          // window col 0..31
        int g = u & 15;                           // granule slot (copied as-is)
        int cc = min(max(sc0 + lc, 0), WW - 1);
        ssrc[i] = cc * 256 + (g << 4);
    }
#define STAGE(rr_, buf_) { \
    const char* srow_ = img + (size_t)(rr_) * ROWB; \
    _Pragma("unroll") \
    for (int i_ = 0; i_ < 8; ++i_) \
        gload_lds16(srow_ + ssrc[i_], (buf_) + i_ * 1024 + (lane << 4)); \
}

    float ea0[4], ea1[4], ea2[4], ea3[4];
    float ds0[4], ds1[4], ds2[4], ds3[4];
    #pragma unroll
    for (int rr = 0; rr < 4; ++rr) {
        ea0[rr] = EPSI; ea1[rr] = EPSI; ea2[rr] = EPSI; ea3[rr] = EPSI;
        ds0[rr] = 0.f;  ds1[rr] = 0.f;  ds2[rr] = 0.f;  ds3[rr] = 0.f;
    }

#define COMPUTE_T(T_, A_, EA_, DS_) \
    if (r >= row0 + (T_) - NSS && r <= row0 + (T_) + NSS) { \
        f32x4 c0 = {0.f, 0.f, 0.f, 0.f}, c1 = {0.f, 0.f, 0.f, 0.f}; \
        __builtin_amdgcn_s_setprio(1); \
        _Pragma("unroll") for (int kb = 0; kb < 4; ++kb) \
            c0 = __builtin_amdgcn_mfma_f32_16x16x32_bf16(A_[kb], b0[kb], c0, 0, 0, 0); \
        _Pragma("unroll") for (int kb = 0; kb < 4; ++kb) \
            c1 = __builtin_amdgcn_mfma_f32_16x16x32_bf16(A_[kb], b1[kb], c1, 0, 0, 0); \
        __builtin_amdgcn_s_setprio(0); \
        _Pragma("unroll") for (int rr = 0; rr < 4; ++rr) { \
            float d_ = ((msel >> rr) & 1) ? c1[rr] : c0[rr]; \
            EA_[rr] += fast_exp2(d_); DS_[rr] += d_; \
        } \
    }

    int rs = max(row0 - NSS, 0);
    int re = min(row0 + 3 + NSS, HH - 1);

    STAGE(rs, smem);

    for (int r = rs; r <= re; ++r) {
        char* cbuf = smem + ((r - rs) & 1) * WBYTES;
        if (r < re) {
            char* nbuf = smem + ((((r - rs) & 1) ^ 1) * WBYTES);
            STAGE(r + 1, nbuf);
            // wave-private pacing: S(r)'s 8 oldest retire; S(r+1)'s 8 stay in flight
            asm volatile("s_waitcnt vmcnt(8)" ::: "memory");
        } else {
            asm volatile("s_waitcnt vmcnt(0)" ::: "memory");
        }

        short8v b0[4], b1[4];
        #pragma unroll
        for (int kb = 0; kb < 4; ++kb) b0[kb] = *(const short8v*)(cbuf + boff[0][kb]);
        #pragma unroll
        for (int kb = 0; kb < 4; ++kb) b1[kb] = *(const short8v*)(cbuf + boff[1][kb]);

        COMPUTE_T(0, a0, ea0, ds0)
        COMPUTE_T(1, a1, ea1, ds1)
        COMPUTE_T(2, a2, ea2, ds2)
        COMPUTE_T(3, a3, ea3, ds3)
    }

    // Epilogue: deferred masks, weights, wave reduce (log2 form: ln(x)=LN2*log2(x))
    float acc = 0.f;
#define EPI_T(T_, EA_, DS_) { \
    int row = row0 + (T_); \
    float nvd = (float)(min(NSS, row) + min(NSS, HH - 1 - row) + 1); \
    _Pragma("unroll") for (int rr = 0; rr < 4; ++rr) { \
        int wm = wbase + kq * 4 + rr; \
        int nwd = min(NSS, wm) + min(NSS, WW - 1 - wm) + 1; \
        float iw = LN2F / (nvd * (float)nwd); \
        float m_ = (mb & (1u << rr)) ? 1.0f : 0.0f; \
        acc += m_ * iw * (nvd * fast_log2(EA_[rr]) - DS_[rr]); \
    } \
}
    EPI_T(0, ea0, ds0)
    EPI_T(1, ea1, ds1)
    EPI_T(2, ea2, ds2)
    EPI_T(3, ea3, ds3)

    float tot = acc * (1.0f / (4.0f * 65536.0f));
    #pragma unroll
    for (int off = 32; off >= 1; off >>= 1)
        tot += __shfl_down(tot, off);
    if (lane == 0) atomicAdd(out, tot);
}

extern "C" void kernel_launch(void* const* d_in, const int* in_sizes, int n_in,
                              void* d_out, int out_size, void* d_ws, size_t ws_size,
                              hipStream_t stream) {
    const float* feat = (const float*)d_in[0];
    float* out = (float*)d_out;
    __hip_bfloat16* fnorm = (__hip_bfloat16*)d_ws;  // 64MB

    hipFuncSetAttribute(reinterpret_cast<const void*>(&loss_mfma),
                        hipFuncAttributeMaxDynamicSharedMemorySize, 2 * WBYTES);

    hipMemsetAsync(d_out, 0, sizeof(float), stream);
    norm_pack<<<NN * HH * (WW / 64), 256, 0, stream>>>(feat, fnorm);
    loss_mfma<<<NN * 64 * 16, 64, 2 * WBYTES, stream>>>((const char*)fnorm, out);
}

// Round 13
// 62.179 us; speedup vs baseline: 1.7253x; 1.7253x over previous
//
#include <hip/hip_runtime.h>
#include <hip/hip_bf16.h>

#define HH 256
#define WW 256
#define CC 128
#define NN 4
#define NSS 5
#define LN2F 0.6931471805599453f
#define FSCALE 3.79828245f      // sqrt(10*log2(e)); dot scales by 14.4269504089
#define EPSI 1e-6f
#define ROW8 (WW * CC)          // 32768 B per image row in fp8 (256 px * 128 B)
#define SC 80                   // staged cols per row window (c0-8 .. c0+71)
#define SBYTES (SC * 128)       // 10240 B per staged row

typedef __attribute__((ext_vector_type(4))) float f32x4;

__device__ __forceinline__ void gload_lds16(const void* g, void* l) {
    __builtin_amdgcn_global_load_lds(
        (const __attribute__((address_space(1))) unsigned int*)g,
        (__attribute__((address_space(3))) unsigned int*)l, 16, 0, 0);
}

__device__ __forceinline__ float fast_exp2(float x) {
    float r;
    asm("v_exp_f32 %0, %1" : "=v"(r) : "v"(x));
    return r;
}
__device__ __forceinline__ float fast_log2(float x) {
    float r;
    asm("v_log_f32 %0, %1" : "=v"(r) : "v"(x));
    return r;
}

// ---------------- Kernel A: L2-normalize over C (x FSCALE), NCHW(f32) -> NHWC(fp8 e4m3) ----
// Per-pixel layout: 16 units of 8B (8 channels each); unit u stored at slot u^(px&15).
// (16B chunks stay 16B-aligned: chunk c -> slot c^((px&15)>>1), halves swapped if px odd.)
__global__ __launch_bounds__(256) void norm_pack(const float* __restrict__ feat,
                                                 unsigned char* __restrict__ out) {
    __shared__ float lds[64][CC + 2];
    __shared__ float psum[4][64];
    __shared__ float inv[64];
    int bid = blockIdx.x;            // n*1024 + h*4 + wq
    int wq = bid & 3;
    int h = (bid >> 2) & 255;
    int n = bid >> 10;
    int tid = threadIdx.x;
    int p = tid & 63;
    int cg = tid >> 6;
    size_t base = ((size_t)(n * CC) * HH + h) * WW + wq * 64 + p;
    float ss = 0.f;
    #pragma unroll
    for (int i = 0; i < 32; ++i) {
        int c = cg * 32 + i;
        float v = feat[base + (size_t)c * (HH * WW)];
        lds[p][c] = v;
        ss += v * v;
    }
    psum[cg][p] = ss;
    __syncthreads();
    if (tid < 64) {
        float s = psum[0][tid] + psum[1][tid] + psum[2][tid] + psum[3][tid];
        inv[tid] = FSCALE / fmaxf(sqrtf(s), 1e-12f);
    }
    __syncthreads();
    unsigned char* dst = out + (((size_t)n * HH + h) * WW + wq * 64) * CC;
    // 512 chunks of 16B (64 px x 8 chunks); 2 per thread
    #pragma unroll
    for (int k = 0; k < 2; ++k) {
        int j = k * 256 + tid;
        int pp = j >> 3;                 // pixel 0..63
        int c = j & 7;                   // logical 16B chunk (channels 16c..16c+15)
        int slot = c ^ ((pp >> 1) & 7);  // (px&15)>>1 == (pp>>1)&7 (wq*64 = 0 mod 16)
        float iv = inv[pp];
        int cb = c * 16;
        int base0 = cb + ((pp & 1) ? 8 : 0);   // channels for bytes 0-7
        int base1 = cb + ((pp & 1) ? 0 : 8);   // channels for bytes 8-15
        int w0 = 0, w1 = 0, w2 = 0, w3 = 0;
        w0 = __builtin_amdgcn_cvt_pk_fp8_f32(lds[pp][base0+0]*iv, lds[pp][base0+1]*iv, w0, false);
        w0 = __builtin_amdgcn_cvt_pk_fp8_f32(lds[pp][base0+2]*iv, lds[pp][base0+3]*iv, w0, true);
        w1 = __builtin_amdgcn_cvt_pk_fp8_f32(lds[pp][base0+4]*iv, lds[pp][base0+5]*iv, w1, false);
        w1 = __builtin_amdgcn_cvt_pk_fp8_f32(lds[pp][base0+6]*iv, lds[pp][base0+7]*iv, w1, true);
        w2 = __builtin_amdgcn_cvt_pk_fp8_f32(lds[pp][base1+0]*iv, lds[pp][base1+1]*iv, w2, false);
        w2 = __builtin_amdgcn_cvt_pk_fp8_f32(lds[pp][base1+2]*iv, lds[pp][base1+3]*iv, w2, true);
        w3 = __builtin_amdgcn_cvt_pk_fp8_f32(lds[pp][base1+4]*iv, lds[pp][base1+5]*iv, w3, false);
        w3 = __builtin_amdgcn_cvt_pk_fp8_f32(lds[pp][base1+6]*iv, lds[pp][base1+7]*iv, w3, true);
        int4 wv = {w0, w1, w2, w3};
        *(int4*)(dst + pp * 128 + slot * 16) = wv;
    }
}

// ---------------- Kernel B: LDS-staged banded-Gram FP8-MFMA loss, 4 rows/wave ----------------
// R13 = R11 structure with fp8: all memory terms halved. Block = 4 waves,
// owns 4 rows x 64 cols; wave = 4 own rows x 16 cols; two B-tiles (-8,+8)
// shared by all 4 A-row fragments. 2x10KB double-buffer, counted vmcnt.
// ds_read_b64 B-frags, full-unit XOR u^(px&15) -> all 32 banks, conflict-free.
// Select-before-exp (msel); masks/weights deferred; features pre-scaled so
// exp(logit)=2^d. C layout (dtype-indep): col=lane&15, row=(lane>>4)*4+reg.
__global__ __launch_bounds__(256, 4) void loss_mfma(const char* __restrict__ fn,
                                                    float* __restrict__ out) {
    extern __shared__ char smem[];
    __shared__ float wsum[4];
    int bid = blockIdx.x;
    int swz = (bid & 7) * 128 + (bid >> 3);   // 1024 blocks, bijective XCD swizzle
    int n  = swz >> 8;
    int rg = (swz >> 2) & 63;
    int q  = swz & 3;
    int row0 = rg * 4;
    int c0 = q * 64;
    int tid = threadIdx.x;
    int wave = tid >> 6, lane = tid & 63;
    int nloc = lane & 15, kq = lane >> 4;
    int wbase = c0 + wave * 16;
    int sc0 = c0 - 8;

    const char* img = fn + (size_t)n * ((size_t)HH * ROW8);

    // A fragments: own rows row0..row0+3 at col wbase+nloc; unit u=kb*4+kq at slot u^(px&15)
    long a0[4], a1[4], a2[4], a3[4];
    {
        int px = wbase + nloc;
        const char* pb = img + (size_t)row0 * ROW8 + px * 128;
        #pragma unroll
        for (int kb = 0; kb < 4; ++kb) a0[kb] = *(const long*)(pb + (((kb * 4 + kq) ^ (px & 15)) << 3));
        pb += ROW8;
        #pragma unroll
        for (int kb = 0; kb < 4; ++kb) a1[kb] = *(const long*)(pb + (((kb * 4 + kq) ^ (px & 15)) << 3));
        pb += ROW8;
        #pragma unroll
        for (int kb = 0; kb < 4; ++kb) a2[kb] = *(const long*)(pb + (((kb * 4 + kq) ^ (px & 15)) << 3));
        pb += ROW8;
        #pragma unroll
        for (int kb = 0; kb < 4; ++kb) a3[kb] = *(const long*)(pb + (((kb * 4 + kq) ^ (px & 15)) << 3));
    }

    // B-fragment LDS offsets (tiles at wbase-8, wbase+8), buffer-local, swizzle-matched
    int boff[2][4];
    #pragma unroll
    for (int j = 0; j < 2; ++j) {
        int colr = wbase - 8 + 16 * j + nloc;     // in [c0-8, c0+71]
        int lcol = colr - sc0;                    // 0..79
        int cc = min(max(colr, 0), WW - 1);       // pixel actually stored there
        #pragma unroll
        for (int kb = 0; kb < 4; ++kb)
            boff[j][kb] = lcol * 128 + (((kb * 4 + kq) ^ (cc & 15)) << 3);
    }

    // selection (tile1 valid?) + any-valid bits per rr; dy/row-invariant
    unsigned msel = 0, mb = 0;
    #pragma unroll
    for (int rr = 0; rr < 4; ++rr) {
        int rm = kq * 4 + rr;
        int dx0 = -8 + nloc - rm, dx1 = 8 + nloc - rm;
        int nc0 = wbase - 8 + nloc, nc1 = wbase + 8 + nloc;
        bool v0 = dx0 >= -NSS && dx0 <= NSS && nc0 >= 0 && nc0 < WW;
        bool v1 = dx1 >= -NSS && dx1 <= NSS && nc1 >= 0 && nc1 < WW;
        if (v1) msel |= 1u << rr;
        if (v0 || v1) mb |= 1u << rr;
    }

    // staging: 640 16B chunks per row; threads get chunk tid, tid+256, and (tid<128) tid+512
    int ss0, ss1, ss2;
    {
        int ch, cc_;
        ch = tid;        cc_ = min(max(sc0 + (ch >> 3), 0), WW - 1); ss0 = cc_ * 128 + ((ch & 7) << 4);
        ch = 256 + tid;  cc_ = min(max(sc0 + (ch >> 3), 0), WW - 1); ss1 = cc_ * 128 + ((ch & 7) << 4);
        ch = 512 + tid;  cc_ = min(max(sc0 + (ch >> 3), 0), WW - 1); ss2 = cc_ * 128 + ((ch & 7) << 4);
    }
#define STAGE(rr_, buf_) { \
    const char* srow_ = img + (size_t)(rr_) * ROW8; \
    gload_lds16(srow_ + ss0, (buf_) + (tid << 4)); \
    gload_lds16(srow_ + ss1, (buf_) + ((256 + tid) << 4)); \
    if (tid < 128) gload_lds16(srow_ + ss2, (buf_) + ((512 + tid) << 4)); \
}

    float ea0[4], ea1[4], ea2[4], ea3[4];
    float ds0[4], ds1[4], ds2[4], ds3[4];
    #pragma unroll
    for (int rr = 0; rr < 4; ++rr) {
        ea0[rr] = EPSI; ea1[rr] = EPSI; ea2[rr] = EPSI; ea3[rr] = EPSI;
        ds0[rr] = 0.f;  ds1[rr] = 0.f;  ds2[rr] = 0.f;  ds3[rr] = 0.f;
    }

#define COMPUTE_T(T_, A_, EA_, DS_) \
    if (r >= row0 + (T_) - NSS && r <= row0 + (T_) + NSS) { \
        f32x4 c0 = {0.f, 0.f, 0.f, 0.f}, c1 = {0.f, 0.f, 0.f, 0.f}; \
        __builtin_amdgcn_s_setprio(1); \
        _Pragma("unroll") for (int kb = 0; kb < 4; ++kb) \
            c0 = __builtin_amdgcn_mfma_f32_16x16x32_fp8_fp8(A_[kb], b0[kb], c0, 0, 0, 0); \
        _Pragma("unroll") for (int kb = 0; kb < 4; ++kb) \
            c1 = __builtin_amdgcn_mfma_f32_16x16x32_fp8_fp8(A_[kb], b1[kb], c1, 0, 0, 0); \
        __builtin_amdgcn_s_setprio(0); \
        _Pragma("unroll") for (int rr = 0; rr < 4; ++rr) { \
            float d_ = ((msel >> rr) & 1) ? c1[rr] : c0[rr]; \
            EA_[rr] += fast_exp2(d_); DS_[rr] += d_; \
        } \
    }

    int rs = max(row0 - NSS, 0);
    int re = min(row0 + 3 + NSS, HH - 1);

    STAGE(rs, smem);

    for (int r = rs; r <= re; ++r) {
        char* cbuf = smem + ((r - rs) & 1) * SBYTES;
        if (r < re) {
            char* nbuf = smem + ((((r - rs) & 1) ^ 1) * SBYTES);
            STAGE(r + 1, nbuf);
            // S(r) done; S(r+1) stays in flight (per-wave instr count: w0-1=3, w2-3=2)
            if (tid < 128) asm volatile("s_waitcnt vmcnt(3)" ::: "memory");
            else           asm volatile("s_waitcnt vmcnt(2)" ::: "memory");
        } else {
            asm volatile("s_waitcnt vmcnt(0)" ::: "memory");
        }
        __builtin_amdgcn_s_barrier();
        asm volatile("" ::: "memory");

        long b0[4], b1[4];
        #pragma unroll
        for (int kb = 0; kb < 4; ++kb) b0[kb] = *(const long*)(cbuf + boff[0][kb]);
        #pragma unroll
        for (int kb = 0; kb < 4; ++kb) b1[kb] = *(const long*)(cbuf + boff[1][kb]);

        COMPUTE_T(0, a0, ea0, ds0)
        COMPUTE_T(1, a1, ea1, ds1)
        COMPUTE_T(2, a2, ea2, ds2)
        COMPUTE_T(3, a3, ea3, ds3)

        __builtin_amdgcn_s_barrier();
    }

    // Epilogue: deferred masks, weights, reduce (log2 form: ln(x)=LN2*log2(x))
    float acc = 0.f;
#define EPI_T(T_, EA_, DS_) { \
    int row = row0 + (T_); \
    float nvd = (float)(min(NSS, row) + min(NSS, HH - 1 - row) + 1); \
    _Pragma("unroll") for (int rr = 0; rr < 4; ++rr) { \
        int wm = wbase + kq * 4 + rr; \
        int nwd = min(NSS, wm) + min(NSS, WW - 1 - wm) + 1; \
        float iw = LN2F / (nvd * (float)nwd); \
        float m_ = (mb & (1u << rr)) ? 1.0f : 0.0f; \
        acc += m_ * iw * (nvd * fast_log2(EA_[rr]) - DS_[rr]); \
    } \
}
    EPI_T(0, ea0, ds0)
    EPI_T(1, ea1, ds1)
    EPI_T(2, ea2, ds2)
    EPI_T(3, ea3, ds3)

    float tot = acc * (1.0f / (4.0f * 65536.0f));
    #pragma unroll
    for (int off = 32; off >= 1; off >>= 1)
        tot += __shfl_down(tot, off);
    if (lane == 0) wsum[wave] = tot;
    __syncthreads();
    if (tid == 0) atomicAdd(out, wsum[0] + wsum[1] + wsum[2] + wsum[3]);
}

extern "C" void kernel_launch(void* const* d_in, const int* in_sizes, int n_in,
                              void* d_out, int out_size, void* d_ws, size_t ws_size,
                              hipStream_t stream) {
    const float* feat = (const float*)d_in[0];
    float* out = (float*)d_out;
    unsigned char* fnorm = (unsigned char*)d_ws;  // 32MB fp8

    hipFuncSetAttribute(reinterpret_cast<const void*>(&loss_mfma),
                        hipFuncAttributeMaxDynamicSharedMemorySize, 2 * SBYTES);

    hipMemsetAsync(d_out, 0, sizeof(float), stream);
    norm_pack<<<NN * HH * (WW / 64), 256, 0, stream>>>(feat, fnorm);
    loss_mfma<<<NN * 64 * 4, 256, 2 * SBYTES, stream>>>((const char*)fnorm, out);
}

// Round 14
// 59.840 us; speedup vs baseline: 1.7927x; 1.0391x over previous
//
#include <hip/hip_runtime.h>
#include <hip/hip_bf16.h>

#define HH 256
#define WW 256
#define CC 128
#define NN 4
#define NSS 5
#define LN2F 0.6931471805599453f
#define FSCALE 3.79828245f      // sqrt(10*log2(e)); dot scales by 14.4269504089
#define EPSI 1e-6f
#define ROW8 (WW * CC)          // 32768 B per image row in fp8 (256 px * 128 B)
#define SC 80                   // staged cols per row window (c0-8 .. c0+71)
#define SBYTES (SC * 128)       // 10240 B per staged row

typedef __attribute__((ext_vector_type(4))) float f32x4;

__device__ __forceinline__ void gload_lds16(const void* g, void* l) {
    __builtin_amdgcn_global_load_lds(
        (const __attribute__((address_space(1))) unsigned int*)g,
        (__attribute__((address_space(3))) unsigned int*)l, 16, 0, 0);
}

__device__ __forceinline__ float fast_exp2(float x) {
    float r;
    asm("v_exp_f32 %0, %1" : "=v"(r) : "v"(x));
    return r;
}
__device__ __forceinline__ float fast_log2(float x) {
    float r;
    asm("v_log_f32 %0, %1" : "=v"(r) : "v"(x));
    return r;
}

// ---------------- Kernel A: L2-normalize over C (x FSCALE), NCHW(f32) -> NHWC(fp8 e4m3) ----
// Per-pixel layout: 16 units of 8B (8 channels each); unit u stored at slot u^(px&15).
// Also zeroes d_out (block 0), replacing a separate memset dispatch.
__global__ __launch_bounds__(256) void norm_pack(const float* __restrict__ feat,
                                                 unsigned char* __restrict__ out,
                                                 float* __restrict__ lossout) {
    __shared__ float lds[64][CC + 2];
    __shared__ float psum[4][64];
    __shared__ float inv[64];
    int bid = blockIdx.x;            // n*1024 + h*4 + wq
    if (bid == 0 && threadIdx.x == 0) lossout[0] = 0.f;
    int wq = bid & 3;
    int h = (bid >> 2) & 255;
    int n = bid >> 10;
    int tid = threadIdx.x;
    int p = tid & 63;
    int cg = tid >> 6;
    size_t base = ((size_t)(n * CC) * HH + h) * WW + wq * 64 + p;
    float ss = 0.f;
    #pragma unroll
    for (int i = 0; i < 32; ++i) {
        int c = cg * 32 + i;
        float v = feat[base + (size_t)c * (HH * WW)];
        lds[p][c] = v;
        ss += v * v;
    }
    psum[cg][p] = ss;
    __syncthreads();
    if (tid < 64) {
        float s = psum[0][tid] + psum[1][tid] + psum[2][tid] + psum[3][tid];
        inv[tid] = FSCALE / fmaxf(sqrtf(s), 1e-12f);
    }
    __syncthreads();
    unsigned char* dst = out + (((size_t)n * HH + h) * WW + wq * 64) * CC;
    // 512 chunks of 16B (64 px x 8 chunks); 2 per thread
    #pragma unroll
    for (int k = 0; k < 2; ++k) {
        int j = k * 256 + tid;
        int pp = j >> 3;                 // pixel 0..63
        int c = j & 7;                   // logical 16B chunk (channels 16c..16c+15)
        int slot = c ^ ((pp >> 1) & 7);  // (px&15)>>1 == (pp>>1)&7 (wq*64 = 0 mod 16)
        float iv = inv[pp];
        int cb = c * 16;
        int base0 = cb + ((pp & 1) ? 8 : 0);   // channels for bytes 0-7
        int base1 = cb + ((pp & 1) ? 0 : 8);   // channels for bytes 8-15
        int w0 = 0, w1 = 0, w2 = 0, w3 = 0;
        w0 = __builtin_amdgcn_cvt_pk_fp8_f32(lds[pp][base0+0]*iv, lds[pp][base0+1]*iv, w0, false);
        w0 = __builtin_amdgcn_cvt_pk_fp8_f32(lds[pp][base0+2]*iv, lds[pp][base0+3]*iv, w0, true);
        w1 = __builtin_amdgcn_cvt_pk_fp8_f32(lds[pp][base0+4]*iv, lds[pp][base0+5]*iv, w1, false);
        w1 = __builtin_amdgcn_cvt_pk_fp8_f32(lds[pp][base0+6]*iv, lds[pp][base0+7]*iv, w1, true);
        w2 = __builtin_amdgcn_cvt_pk_fp8_f32(lds[pp][base1+0]*iv, lds[pp][base1+1]*iv, w2, false);
        w2 = __builtin_amdgcn_cvt_pk_fp8_f32(lds[pp][base1+2]*iv, lds[pp][base1+3]*iv, w2, true);
        w3 = __builtin_amdgcn_cvt_pk_fp8_f32(lds[pp][base1+4]*iv, lds[pp][base1+5]*iv, w3, false);
        w3 = __builtin_amdgcn_cvt_pk_fp8_f32(lds[pp][base1+6]*iv, lds[pp][base1+7]*iv, w3, true);
        int4 wv = {w0, w1, w2, w3};
        *(int4*)(dst + pp * 128 + slot * 16) = wv;
    }
}

// ---------------- Kernel B: LDS-staged banded-Gram FP8-MFMA loss, 8 rows/wave ----------------
// Block = 4 waves, owns 8 rows x 64 cols; wave = 8 own rows x 16 cols. Two fp8
// B-tiles (-8,+8) per staged row shared by ALL 8 A-row fragments:
// staged bytes/own-px = 18 rows x 10KB / 512 px = 0.44KB (was 0.70 in R13).
// 2x10KB double-buffer, counted vmcnt, two barriers/row. 512 blocks.
// ds_read_b64 B-frags, full-unit XOR u^(px&15): 16 lanes -> 32 banks, conflict-free.
// Select-before-exp (msel); masks/weights deferred; features pre-scaled so
// exp(logit)=2^d. C layout (dtype-indep): col=lane&15, row=(lane>>4)*4+reg.
__global__ __launch_bounds__(256, 2) void loss_mfma(const char* __restrict__ fn,
                                                    float* __restrict__ out) {
    extern __shared__ char smem[];
    __shared__ float wsum[4];
    int bid = blockIdx.x;
    int swz = (bid & 7) * 64 + (bid >> 3);    // 512 blocks, bijective XCD swizzle
    int n  = swz >> 7;
    int rg = (swz >> 2) & 31;
    int q  = swz & 3;
    int row0 = rg * 8;
    int c0 = q * 64;
    int tid = threadIdx.x;
    int wave = tid >> 6, lane = tid & 63;
    int nloc = lane & 15, kq = lane >> 4;
    int wbase = c0 + wave * 16;
    int sc0 = c0 - 8;

    const char* img = fn + (size_t)n * ((size_t)HH * ROW8);

    // A fragments: own rows row0..row0+7 at col wbase+nloc; unit u=kb*4+kq at slot u^(px&15)
    long a[8][4];
    {
        int px = wbase + nloc;
        int xo = px & 15;
        const char* pb = img + (size_t)row0 * ROW8 + px * 128;
        #pragma unroll
        for (int t = 0; t < 8; ++t) {
            #pragma unroll
            for (int kb = 0; kb < 4; ++kb)
                a[t][kb] = *(const long*)(pb + (((kb * 4 + kq) ^ xo) << 3));
            pb += ROW8;
        }
    }

    // B-fragment LDS offsets (tiles at wbase-8, wbase+8), buffer-local, swizzle-matched
    int boff[2][4];
    #pragma unroll
    for (int j = 0; j < 2; ++j) {
        int colr = wbase - 8 + 16 * j + nloc;     // in [c0-8, c0+71]
        int lcol = colr - sc0;                    // 0..79
        int cc = min(max(colr, 0), WW - 1);       // pixel actually stored there
        #pragma unroll
        for (int kb = 0; kb < 4; ++kb)
            boff[j][kb] = lcol * 128 + (((kb * 4 + kq) ^ (cc & 15)) << 3);
    }

    // selection (tile1 valid?) + any-valid bits per rr; dy/row-invariant
    unsigned msel = 0, mb = 0;
    #pragma unroll
    for (int rr = 0; rr < 4; ++rr) {
        int rm = kq * 4 + rr;
        int dx0 = -8 + nloc - rm, dx1 = 8 + nloc - rm;
        int nc0 = wbase - 8 + nloc, nc1 = wbase + 8 + nloc;
        bool v0 = dx0 >= -NSS && dx0 <= NSS && nc0 >= 0 && nc0 < WW;
        bool v1 = dx1 >= -NSS && dx1 <= NSS && nc1 >= 0 && nc1 < WW;
        if (v1) msel |= 1u << rr;
        if (v0 || v1) mb |= 1u << rr;
    }

    // staging: 640 16B chunks per row; threads get chunk tid, tid+256, and (tid<128) tid+512
    int ss0, ss1, ss2;
    {
        int ch, cc_;
        ch = tid;        cc_ = min(max(sc0 + (ch >> 3), 0), WW - 1); ss0 = cc_ * 128 + ((ch & 7) << 4);
        ch = 256 + tid;  cc_ = min(max(sc0 + (ch >> 3), 0), WW - 1); ss1 = cc_ * 128 + ((ch & 7) << 4);
        ch = 512 + tid;  cc_ = min(max(sc0 + (ch >> 3), 0), WW - 1); ss2 = cc_ * 128 + ((ch & 7) << 4);
    }
#define STAGE(rr_, buf_) { \
    const char* srow_ = img + (size_t)(rr_) * ROW8; \
    gload_lds16(srow_ + ss0, (buf_) + (tid << 4)); \
    gload_lds16(srow_ + ss1, (buf_) + ((256 + tid) << 4)); \
    if (tid < 128) gload_lds16(srow_ + ss2, (buf_) + ((512 + tid) << 4)); \
}

    float ea[8][4], dsm[8][4];
    #pragma unroll
    for (int t = 0; t < 8; ++t)
        #pragma unroll
        for (int rr = 0; rr < 4; ++rr) { ea[t][rr] = EPSI; dsm[t][rr] = 0.f; }

    int rs = max(row0 - NSS, 0);
    int re = min(row0 + 7 + NSS, HH - 1);

    STAGE(rs, smem);

    for (int r = rs; r <= re; ++r) {
        char* cbuf = smem + ((r - rs) & 1) * SBYTES;
        if (r < re) {
            char* nbuf = smem + ((((r - rs) & 1) ^ 1) * SBYTES);
            STAGE(r + 1, nbuf);
            // S(r) done; S(r+1) stays in flight (per-thread stage instr: 3 | 2)
            if (tid < 128) asm volatile("s_waitcnt vmcnt(3)" ::: "memory");
            else           asm volatile("s_waitcnt vmcnt(2)" ::: "memory");
        } else {
            asm volatile("s_waitcnt vmcnt(0)" ::: "memory");
        }
        __builtin_amdgcn_s_barrier();
        asm volatile("" ::: "memory");

        long b0[4], b1[4];
        #pragma unroll
        for (int kb = 0; kb < 4; ++kb) b0[kb] = *(const long*)(cbuf + boff[0][kb]);
        #pragma unroll
        for (int kb = 0; kb < 4; ++kb) b1[kb] = *(const long*)(cbuf + boff[1][kb]);

        #pragma unroll
        for (int t = 0; t < 8; ++t) {
            if (r >= row0 + t - NSS && r <= row0 + t + NSS) {
                f32x4 c0 = {0.f, 0.f, 0.f, 0.f}, c1 = {0.f, 0.f, 0.f, 0.f};
                __builtin_amdgcn_s_setprio(1);
                #pragma unroll
                for (int kb = 0; kb < 4; ++kb)
                    c0 = __builtin_amdgcn_mfma_f32_16x16x32_fp8_fp8(a[t][kb], b0[kb], c0, 0, 0, 0);
                #pragma unroll
                for (int kb = 0; kb < 4; ++kb)
                    c1 = __builtin_amdgcn_mfma_f32_16x16x32_fp8_fp8(a[t][kb], b1[kb], c1, 0, 0, 0);
                __builtin_amdgcn_s_setprio(0);
                #pragma unroll
                for (int rr = 0; rr < 4; ++rr) {
                    float d_ = ((msel >> rr) & 1) ? c1[rr] : c0[rr];
                    ea[t][rr] += fast_exp2(d_);
                    dsm[t][rr] += d_;
                }
            }
        }

        __builtin_amdgcn_s_barrier();
    }

    // Epilogue: deferred masks, weights, reduce (log2 form: ln(x)=LN2*log2(x))
    float acc = 0.f;
    #pragma unroll
    for (int t = 0; t < 8; ++t) {
        int row = row0 + t;
        float nvd = (float)(min(NSS, row) + min(NSS, HH - 1 - row) + 1);
        #pragma unroll
        for (int rr = 0; rr < 4; ++rr) {
            int wm = wbase + kq * 4 + rr;
            int nwd = min(NSS, wm) + min(NSS, WW - 1 - wm) + 1;
            float iw = LN2F / (nvd * (float)nwd);
            float m_ = (mb & (1u << rr)) ? 1.0f : 0.0f;
            acc += m_ * iw * (nvd * fast_log2(ea[t][rr]) - dsm[t][rr]);
        }
    }

    float tot = acc * (1.0f / (4.0f * 65536.0f));
    #pragma unroll
    for (int off = 32; off >= 1; off >>= 1)
        tot += __shfl_down(tot, off);
    if (lane == 0) wsum[wave] = tot;
    __syncthreads();
    if (tid == 0) atomicAdd(out, wsum[0] + wsum[1] + wsum[2] + wsum[3]);
}

extern "C" void kernel_launch(void* const* d_in, const int* in_sizes, int n_in,
                              void* d_out, int out_size, void* d_ws, size_t ws_size,
                              hipStream_t stream) {
    const float* feat = (const float*)d_in[0];
    float* out = (float*)d_out;
    unsigned char* fnorm = (unsigned char*)d_ws;  // 32MB fp8

    hipFuncSetAttribute(reinterpret_cast<const void*>(&loss_mfma),
                        hipFuncAttributeMaxDynamicSharedMemorySize, 2 * SBYTES);

    norm_pack<<<NN * HH * (WW / 64), 256, 0, stream>>>(feat, fnorm, out);
    loss_mfma<<<NN * 32 * 4, 256, 2 * SBYTES, stream>>>((const char*)fnorm, out);
}